// Round 1
// baseline (386.088 us; speedup 1.0000x reference)
//
#include <hip/hip_runtime.h>

// 256 independent LSAP problems (Jonker-Volgenant shortest augmenting path),
// one wave (64 lanes) per problem, lane j owns column j.
// All dual/path arithmetic in double with numpy-identical expression order.

__global__ __launch_bounds__(64)
void lsap_solve(const float* __restrict__ cost,
                const float* __restrict__ gt,
                float* __restrict__ out,
                double* __restrict__ partial)
{
    const int b    = blockIdx.x;
    const int lane = threadIdx.x;          // 0..63, column index
    const double INF = __builtin_inf();

    __shared__ float  costL[64 * 64];      // row-major [row][col]
    __shared__ double uL[64];              // row duals
    __shared__ double minvL[64];           // spilled minv for cross-lane gather
    __shared__ int    pathL[64];           // predecessor row per column
    __shared__ int    row4colL[64];
    __shared__ int    col4rowL[64];
    __shared__ int    ordL[64];

    // ---- stage cost matrix to LDS (coalesced float4) ----
    const float4* cb4 = (const float4*)(cost + (size_t)b * 4096);
    float4*       cl4 = (float4*)costL;
#pragma unroll
    for (int i = 0; i < 16; ++i)
        cl4[i * 64 + lane] = cb4[i * 64 + lane];

    // ---- valid-box count: first all-zero [2,3] box ----
    const float* gb = gt + (size_t)b * 384 + lane * 6;
    bool iszero = true;
#pragma unroll
    for (int k = 0; k < 6; ++k) iszero = iszero && (gb[k] == 0.0f);
    unsigned long long zmask = __ballot(iszero);
    const int c = zmask ? (__ffsll((unsigned long long)zmask) - 1) : 64;

    uL[lane]       = 0.0;
    pathL[lane]    = -1;
    row4colL[lane] = -1;
    col4rowL[lane] = -1;
    double v_l = 0.0;                      // column dual (lane-private)
    __syncthreads();

    for (int cur_row = 0; cur_row < c; ++cur_row) {
        double minv      = INF;            // lane-private: shortest path cost to column `lane`
        bool   remaining = true;
        unsigned long long SR = 0ULL;      // scanned-rows mask (wave-uniform)
        int    i       = cur_row;          // wave-uniform
        double min_val = 0.0;              // wave-uniform
        int    sink    = -1;

        while (sink < 0) {
            SR |= 1ULL << i;
            const double u_i = uL[i];      // uniform broadcast read
            if (remaining) {
                // numpy order: ((min_val + cost) - u) - v   (adds/subs only -> no contraction)
                double r = min_val + (double)costL[i * 64 + lane] - u_i - v_l;
                if (r < minv) { minv = r; pathL[lane] = i; }
            }
            // wave argmin over remaining columns, first-index tie-break (== np.argmin)
            double key = remaining ? minv : INF;
            int    idx = lane;
#pragma unroll
            for (int s = 1; s < 64; s <<= 1) {
                double ok = __shfl_xor(key, s, 64);
                int    oi = __shfl_xor(idx, s, 64);
                if (ok < key || (ok == key && oi < idx)) { key = ok; idx = oi; }
            }
            min_val = key;
            const int jsel = idx;
            if (lane == jsel) remaining = false;
            const int rj = row4colL[jsel]; // uniform broadcast read
            if (rj < 0) sink = jsel; else i = rj;
        }

        minvL[lane] = minv;
        __syncthreads();

        // ---- dual updates (exactly the reference formulas) ----
        if (lane == cur_row) {
            uL[lane] += min_val;
        } else if ((SR >> lane) & 1ULL) {
            uL[lane] += min_val - minvL[col4rowL[lane]];
        }
        if (!remaining) v_l -= min_val - minv;   // scanned columns
        __syncthreads();

        // ---- augment along alternating path (uniform scalar work, lane 0) ----
        if (lane == 0) {
            int jj = sink;
            while (true) {
                const int ii = pathL[jj];
                row4colL[jj] = ii;
                const int tmp = col4rowL[ii];
                col4rowL[ii] = jj;
                jj = tmp;
                if (ii == cur_row) break;
            }
        }
        __syncthreads();
    }

    // ---- ordering = concat(col4row[0:c], sorted unassigned columns) ----
    const bool assigned = (row4colL[lane] >= 0);
    const unsigned long long amask = __ballot(assigned);
    if (lane < c) ordL[lane] = col4rowL[lane];
    if (!assigned) {
        const unsigned long long below = (~amask) & ((1ULL << lane) - 1ULL);
        ordL[c + __popcll(below)] = lane;
    }
    __syncthreads();

    const int oc = ordL[lane];
    out[b * 64 + lane] = (float)oc;

    // ---- per-block loss partial: sum_r cost[r, ordering[r]] ----
    double p = (double)costL[lane * 64 + oc];
#pragma unroll
    for (int s = 1; s < 64; s <<= 1) p += __shfl_xor(p, s, 64);
    if (lane == 0) partial[b] = p;
}

__global__ __launch_bounds__(256)
void loss_reduce(const double* __restrict__ partial, float* __restrict__ out,
                 int B)
{
    const int t = threadIdx.x;
    __shared__ double sb[4];
    double p = 0.0;
    for (int idx = t; idx < B; idx += 256) p += partial[idx];
#pragma unroll
    for (int s = 1; s < 64; s <<= 1) p += __shfl_xor(p, s, 64);
    if ((t & 63) == 0) sb[t >> 6] = p;
    __syncthreads();
    if (t == 0)
        out[B * 64] = (float)((sb[0] + sb[1] + sb[2] + sb[3]) / (double)(B * 64));
}

extern "C" void kernel_launch(void* const* d_in, const int* in_sizes, int n_in,
                              void* d_out, int out_size, void* d_ws, size_t ws_size,
                              hipStream_t stream)
{
    const float* cost = (const float*)d_in[0];   // [B,64,64] f32
    const float* gt   = (const float*)d_in[1];   // [B,64,2,3] f32
    float* out        = (float*)d_out;           // [B*64] ordering + [1] loss
    double* partial   = (double*)d_ws;           // B doubles of scratch

    const int B = in_sizes[0] / 4096;            // 64*64 per problem

    lsap_solve<<<B, 64, 0, stream>>>(cost, gt, out, partial);
    loss_reduce<<<1, 256, 0, stream>>>(partial, out, B);
}

// Round 3
// 115.282 us; speedup vs baseline: 3.3491x; 3.3491x over previous
//
#include <hip/hip_runtime.h>

// 256 independent LSAP problems (Jonker-Volgenant), one wave per problem,
// lane j owns column j AND row j's dual state. All solver state in registers;
// cross-lane via DPP/readlane + predicated writes (VALU/SALU), LDS only for
// the cost matrix. All arithmetic double, numpy-identical expression order.

union DU { double d; int i2[2]; };

__device__ inline double readlane_f64(double x, int l) {
    DU a; a.d = x;
    DU o;
    o.i2[0] = __builtin_amdgcn_readlane(a.i2[0], l);
    o.i2[1] = __builtin_amdgcn_readlane(a.i2[1], l);
    return o.d;
}

template <int CTRL>
__device__ inline double dpp_min_f64(double x) {
    DU a; a.d = x;
    DU b;
    b.i2[0] = __builtin_amdgcn_update_dpp(0, a.i2[0], CTRL, 0xF, 0xF, true);
    b.i2[1] = __builtin_amdgcn_update_dpp(0, a.i2[1], CTRL, 0xF, 0xF, true);
    return fmin(x, b.d);
}

__global__ __launch_bounds__(64)
void lsap_solve(const float* __restrict__ cost,
                const float* __restrict__ gt,
                float* __restrict__ out,
                double* __restrict__ partial)
{
    const int b    = blockIdx.x;
    const int lane = threadIdx.x;          // column index (and row index for u)
    const double INF = __builtin_inf();

    __shared__ float costL[64 * 64];       // row-major [row][col]
    __shared__ int   ordL[64];

    // ---- stage cost matrix to LDS (coalesced float4) ----
    const float4* cb4 = (const float4*)(cost + (size_t)b * 4096);
    float4*       cl4 = (float4*)costL;
#pragma unroll
    for (int i = 0; i < 16; ++i)
        cl4[i * 64 + lane] = cb4[i * 64 + lane];

    // ---- valid-box count: first all-zero [2,3] box ----
    const float* gb = gt + (size_t)b * 384 + lane * 6;
    bool iszero = true;
#pragma unroll
    for (int k = 0; k < 6; ++k) iszero = iszero && (gb[k] == 0.0f);
    unsigned long long zmask = __ballot(iszero);
    const int c = zmask ? (__ffsll(zmask) - 1) : 64;

    // ---- lane-private solver state ----
    double u_d = 0.0;          // u[lane]       (lane as row)
    double v_d = 0.0;          // v[lane]       (lane as col)
    int path_r    = -1;        // path[lane]    (lane as col)
    int row4col_r = -1;        // row4col[lane] (lane as col)
    int col4row_r = -1;        // col4row[lane] (lane as row)

    __syncthreads();           // costL visible

    for (int cur_row = 0; cur_row < c; ++cur_row) {
        double minv_d    = INF;    // shortest path cost to column `lane`
        bool   remaining = true;
        unsigned long long SR = 0ULL;
        int    i       = cur_row;  // wave-uniform
        double min_val = 0.0;
        int    sink    = -1;

        while (sink < 0) {
            SR |= 1ULL << i;
            const double u_i = readlane_f64(u_d, i);        // SALU broadcast
            const float  cf  = costL[i * 64 + lane];        // the one DS op
            // numpy order: ((min_val + cost) - u) - v  (adds only, no FMA)
            double r = min_val + (double)cf;
            r = r - u_i;
            r = r - v_d;
            const bool upd = remaining && (r < minv_d);
            minv_d = upd ? r : minv_d;
            path_r = upd ? i : path_r;

            const double key = remaining ? minv_d : INF;
            // VALU butterfly min: xor1, xor2, (xor4 via half-mirror), (xor8 via mirror)
            double k = dpp_min_f64<0xB1>(key);    // quad_perm {1,0,3,2}
            k = dpp_min_f64<0x4E>(k);             // quad_perm {2,3,0,1}
            k = dpp_min_f64<0x141>(k);            // ROW_HALF_MIRROR
            k = dpp_min_f64<0x140>(k);            // ROW_MIRROR -> min of each 16
            const double m0 = readlane_f64(k, 0);
            const double m1 = readlane_f64(k, 16);
            const double m2 = readlane_f64(k, 32);
            const double m3 = readlane_f64(k, 48);
            const double kmin = fmin(fmin(m0, m1), fmin(m2, m3));

            const unsigned long long eq = __ballot(key == kmin);
            const int jsel = __ffsll(eq) - 1;     // lowest lane = np.argmin tie-break
            min_val   = kmin;
            remaining = remaining && (lane != jsel);
            const int rj = __builtin_amdgcn_readlane(row4col_r, jsel);
            if (rj < 0) sink = jsel; else i = rj;
        }

        // ---- dual updates (reference formulas, pre-augment col4row) ----
        {
            const bool scanned_row = (SR >> lane) & 1ULL;
            const int  gidx = col4row_r & 63;               // clamp -1 -> unused
            const double mv_g = __shfl(minv_d, gidx, 64);   // minv[col4row[lane]]
            if (lane == cur_row)       u_d += min_val;
            else if (scanned_row)      u_d += min_val - mv_g;
            if (!remaining)            v_d -= min_val - minv_d;  // scanned cols
        }

        // ---- augment along alternating path (uniform; predicated lane writes) ----
        {
            int jj = sink;
            while (true) {
                const int ii = __builtin_amdgcn_readlane(path_r, jj);
                if (lane == jj) row4col_r = ii;
                const int tmp = __builtin_amdgcn_readlane(col4row_r, ii);
                if (lane == ii) col4row_r = jj;
                jj = tmp;
                if (ii == cur_row) break;
            }
        }
    }

    // ---- ordering = concat(col4row[0:c], sorted unassigned columns) ----
    const bool assigned = (row4col_r >= 0);                 // lane as col
    const unsigned long long amask = __ballot(assigned);
    if (lane < c) ordL[lane] = col4row_r;                   // lane as row
    if (!assigned) {
        const unsigned long long below = (~amask) & ((1ULL << lane) - 1ULL);
        ordL[c + __popcll(below)] = lane;
    }
    __syncthreads();

    const int oc = ordL[lane];
    out[b * 64 + lane] = (float)oc;

    // ---- per-block loss partial: sum_r cost[r, ordering[r]] ----
    double p = (double)costL[lane * 64 + oc];
#pragma unroll
    for (int s = 1; s < 64; s <<= 1) p += __shfl_xor(p, s, 64);
    if (lane == 0) partial[b] = p;
}

__global__ __launch_bounds__(256)
void loss_reduce(const double* __restrict__ partial, float* __restrict__ out,
                 int B)
{
    const int t = threadIdx.x;
    __shared__ double sb[4];
    double p = 0.0;
    for (int idx = t; idx < B; idx += 256) p += partial[idx];
#pragma unroll
    for (int s = 1; s < 64; s <<= 1) p += __shfl_xor(p, s, 64);
    if ((t & 63) == 0) sb[t >> 6] = p;
    __syncthreads();
    if (t == 0)
        out[B * 64] = (float)((sb[0] + sb[1] + sb[2] + sb[3]) / (double)(B * 64));
}

extern "C" void kernel_launch(void* const* d_in, const int* in_sizes, int n_in,
                              void* d_out, int out_size, void* d_ws, size_t ws_size,
                              hipStream_t stream)
{
    const float* cost = (const float*)d_in[0];   // [B,64,64] f32
    const float* gt   = (const float*)d_in[1];   // [B,64,2,3] f32
    float* out        = (float*)d_out;           // [B*64] ordering + [1] loss
    double* partial   = (double*)d_ws;           // B doubles of scratch

    const int B = in_sizes[0] / 4096;            // 64*64 per problem

    lsap_solve<<<B, 64, 0, stream>>>(cost, gt, out, partial);
    loss_reduce<<<1, 256, 0, stream>>>(partial, out, B);
}